// Round 5
// baseline (154.329 us; speedup 1.0000x reference)
//
#include <hip/hip_runtime.h>
#include <hip/hip_fp16.h>
#include <math.h>

// Problem constants (fixed by reference)
#define NI_TOT 100000
#define NJ_TOT 100000
#define DD 8
#define SI_N 6000
#define SJ_N 6000
#define NNZ_N 500000
#define EPSF 1e-6f
#define LOG2E 1.44269504088896f
#define INV_LOG2E 0.693147180559945f

// Dense geometry: block = 64 i-rows (LDS) x 512 j-cols (2/thread in regs).
// R2 lesson: grid must stay >= ~2048 blocks (latency-bound, needs residency).
// R4 lesson: i-rows MUST come via LDS broadcast, NOT scalar s_load chains
// (wave-uniform VMEM scalarized -> lgkmcnt(0) drain per row -> 2x slower).
#define TI 64
#define JPT 2
#define JTILE (256 * JPT)                     // 512
#define ND_I ((SI_N + TI - 1) / TI)           // 94
#define NJT ((SJ_N + JTILE - 1) / JTILE)      // 12
#define N_DENSE_BLOCKS (ND_I * NJT)           // 1128
// Sparse: 2 links per thread
#define LPT 2
#define SPARSE_SPAN (256 * LPT)               // 512
#define N_SPARSE_BLOCKS ((NNZ_N + SPARSE_SPAN - 1) / SPARSE_SPAN) // 977
#define N_TOTAL_BLOCKS (N_DENSE_BLOCKS + N_SPARSE_BLOCKS)         // 2105

// Workspace layout:
//  [fp16 z rows 200K x 16B][fp16 biases 200K x 2B][irec 6016 x 48B]
//  [partials N_TOTAL x 4B][ticket 4B]
// fp16 cache keeps sparse gather footprint 3.6MB (L2-resident per XCD);
// R1 measured: dropping it cost 44MB HBM FETCH.
// irec: per sampled i-row {m_d[8] = -2*LOG2E*(z+EPS), seed=|m|^2/4, e^beta},
// computed ONCE in pack (was recomputed 12x per i-tile in R3's prologue);
// dense blocks stage it to LDS with coalesced float4 (R4 validated irec
// contents; R4's failure was the transport, not the table).
#define NROWS (NI_TOT + NJ_TOT)
#define HZ_BYTES ((size_t)NROWS * DD * 2)     // 3,200,000
#define HB_BYTES ((size_t)NROWS * 2)          // 400,000
#define IREC_N (ND_I * TI)                    // 6016
#define IREC_OFF (HZ_BYTES + HB_BYTES)        // 3,600,000 (16B aligned)
#define IREC_BYTES ((size_t)IREC_N * 12 * 4)  // 288,768
#define PART_OFF (IREC_OFF + IREC_BYTES)      // 3,888,768
#define TICKET_OFF (PART_OFF + (size_t)N_TOTAL_BLOCKS * 4)
#define WS_NEED (TICKET_OFF + 4)

// A&S 6.1.36: Gamma(1+x) = 1 + a1 x + ... + a8 x^8, 0<=x<=1, |eps|<=3e-7
#define GA1 (-0.577191652f)
#define GA2 ( 0.988205891f)
#define GA3 (-0.897056937f)
#define GA4 ( 0.918206857f)
#define GA5 (-0.756704078f)
#define GA6 ( 0.482199394f)
#define GA7 (-0.193527818f)
#define GA8 ( 0.035868343f)

// ---- prep: fp16 tables + dense i-row records + ticket reset ----
__global__ __launch_bounds__(256) void pack_kernel(
    const float* __restrict__ beta, const float* __restrict__ gamma,
    const float* __restrict__ zi_all, const float* __restrict__ zj_all,
    const int* __restrict__ si,
    __half* __restrict__ hz, __half* __restrict__ hb,
    float* __restrict__ irec, unsigned* __restrict__ ticket)
{
    const int r = blockIdx.x * 256 + threadIdx.x;
    if (r == 0) *ticket = 0u;
    if (r < NROWS) {
        const float* src = (r < NI_TOT) ? zi_all + (size_t)r * DD
                                        : zj_all + (size_t)(r - NI_TOT) * DD;
        float4 a = ((const float4*)src)[0];
        float4 b = ((const float4*)src)[1];
        __half2 h0 = __floats2half2_rn(a.x, a.y);
        __half2 h1 = __floats2half2_rn(a.z, a.w);
        __half2 h2 = __floats2half2_rn(b.x, b.y);
        __half2 h3 = __floats2half2_rn(b.z, b.w);
        uint4 u;
        u.x = *(unsigned*)&h0; u.y = *(unsigned*)&h1;
        u.z = *(unsigned*)&h2; u.w = *(unsigned*)&h3;
        ((uint4*)hz)[r] = u;
    } else if (r < 2 * NROWS) {
        const int q = r - NROWS;
        float v = (q < NI_TOT) ? beta[q] : gamma[q - NI_TOT];
        hb[q] = __float2half(v);
    } else if (r < 2 * NROWS + IREC_N) {
        const int q = r - 2 * NROWS;
        float4 m0 = make_float4(0.f, 0.f, 0.f, 0.f);
        float4 m1 = make_float4(0.f, 0.f, 0.f, 0.f);
        float seed = 0.f, eb = 0.f;   // pad rows: eb=0 -> zero contribution
        if (q < SI_N) {
            const int row = si[q];
            const float4* zp = (const float4*)(zi_all + (size_t)row * DD);
            float4 a = zp[0], b = zp[1];
            const float k = -2.0f * LOG2E;
            m0.x = (a.x + EPSF) * k; m0.y = (a.y + EPSF) * k;
            m0.z = (a.z + EPSF) * k; m0.w = (a.w + EPSF) * k;
            m1.x = (b.x + EPSF) * k; m1.y = (b.y + EPSF) * k;
            m1.z = (b.z + EPSF) * k; m1.w = (b.w + EPSF) * k;
            float s = 0.f;
            s = fmaf(m0.x, m0.x, s); s = fmaf(m0.y, m0.y, s);
            s = fmaf(m0.z, m0.z, s); s = fmaf(m0.w, m0.w, s);
            s = fmaf(m1.x, m1.x, s); s = fmaf(m1.y, m1.y, s);
            s = fmaf(m1.z, m1.z, s); s = fmaf(m1.w, m1.w, s);
            seed = 0.25f * s;                       // = |(zi+EPS)*LOG2E|^2
            eb = __builtin_amdgcn_exp2f(beta[row] * LOG2E);
        }
        float4* op = (float4*)(irec + (size_t)q * 12);
        op[0] = m0; op[1] = m1;
        op[2] = make_float4(seed, eb, 0.f, 0.f);
    }
}

__device__ __forceinline__ void unpack_row(uint4 u, float f[DD]) {
    float2 p;
    p = __half22float2(*(__half2*)&u.x); f[0] = p.x; f[1] = p.y;
    p = __half22float2(*(__half2*)&u.y); f[2] = p.x; f[3] = p.y;
    p = __half22float2(*(__half2*)&u.z); f[4] = p.x; f[5] = p.y;
    p = __half22float2(*(__half2*)&u.w); f[6] = p.x; f[7] = p.y;
}

template<int MODE>   // 0 = workspace path, 1 = f32 fallback (atomic out)
__global__ __launch_bounds__(256) void fused_kernel(
    const float* __restrict__ beta, const float* __restrict__ gamma,
    const float* __restrict__ zi_all, const float* __restrict__ zj_all,
    const float* __restrict__ valueC,
    const int* __restrict__ si, const int* __restrict__ sj,       // dense samples
    const int* __restrict__ spi, const int* __restrict__ spj,     // sparse links
    const __half* __restrict__ hz, const __half* __restrict__ hb, // fp16 packed
    const float* __restrict__ irec,                               // i-row records
    float* __restrict__ partials, unsigned* __restrict__ ticket,
    float* __restrict__ out)
{
    __shared__ float sRed[4];
    __shared__ int lastFlag;
    __shared__ __align__(16) float sIR[TI * 12];  // {m[8], seed, eb, pad2} per row

    const int t = threadIdx.x;
    float blocksum = 0.0f;  // signed contribution of this block to LL

    if (blockIdx.x < N_DENSE_BLOCKS) {
        // -------- dense non-link: -sum(exp(beta_i + gamma_j - |zi-zj|)) --------
        // Factored: e^{b+g-d} = (e^b)_row * (e^g)_col * exp2(-LOG2E*d).
        // Hot loop reads rows via LDS BROADCAST (proven transport, R3 vs R4).
        const int it = blockIdx.x % ND_I;
        const int js = blockIdx.x / ND_I;
        const int i0 = it * TI;

        // Stage i-tile records: 192 coalesced float4 (no gather, no recompute,
        // no serial section, ONE barrier -- was 512 scattered + serial + 2 bar).
        if (MODE == 0) {
            const float4* src = (const float4*)(irec + (size_t)i0 * 12);
            float4* dst = (float4*)sIR;
            if (t < TI * 12 / 4) dst[t] = src[t];
        } else {
            // Fallback: build records in-kernel (64-thread section, as R3)
            if (t < TI) {
                const int gi = i0 + t;
                float4 m0 = make_float4(0.f,0.f,0.f,0.f), m1 = m0;
                float seed = 0.f, eb = 0.f;
                if (gi < SI_N) {
                    const int row = si[gi];
                    const float4* zp = (const float4*)(zi_all + (size_t)row * DD);
                    float4 a = zp[0], b = zp[1];
                    const float k = -2.0f * LOG2E;
                    m0.x=(a.x+EPSF)*k; m0.y=(a.y+EPSF)*k; m0.z=(a.z+EPSF)*k; m0.w=(a.w+EPSF)*k;
                    m1.x=(b.x+EPSF)*k; m1.y=(b.y+EPSF)*k; m1.z=(b.z+EPSF)*k; m1.w=(b.w+EPSF)*k;
                    float s = 0.f;
                    s=fmaf(m0.x,m0.x,s); s=fmaf(m0.y,m0.y,s); s=fmaf(m0.z,m0.z,s); s=fmaf(m0.w,m0.w,s);
                    s=fmaf(m1.x,m1.x,s); s=fmaf(m1.y,m1.y,s); s=fmaf(m1.z,m1.z,s); s=fmaf(m1.w,m1.w,s);
                    seed = 0.25f * s;
                    eb = __builtin_amdgcn_exp2f(beta[row] * LOG2E);
                }
                float4* op = (float4*)&sIR[t * 12];
                op[0] = m0; op[1] = m1;
                op[2] = make_float4(seed, eb, 0.f, 0.f);
            }
        }

        // Gather this thread's 2 j-columns into registers (overlaps staging).
        const int jb = js * JTILE + t * JPT;
        float zc[JPT][DD], s2[JPT], gf[JPT];
#pragma unroll
        for (int u = 0; u < JPT; ++u) {
            int gj = jb + u;
            if (gj < SJ_N) {
                int row = sj[gj];
                const float4* q = (const float4*)(zj_all + (size_t)row * DD);
                float4 q0 = q[0], q1 = q[1];
                zc[u][0]=q0.x*LOG2E; zc[u][1]=q0.y*LOG2E; zc[u][2]=q0.z*LOG2E; zc[u][3]=q0.w*LOG2E;
                zc[u][4]=q1.x*LOG2E; zc[u][5]=q1.y*LOG2E; zc[u][6]=q1.z*LOG2E; zc[u][7]=q1.w*LOG2E;
                gf[u] = __builtin_amdgcn_exp2f(gamma[row] * LOG2E);
            } else {
#pragma unroll
                for (int d = 0; d < DD; ++d) zc[u][d] = 0.0f;
                gf[u] = 0.0f;  // pad col -> zero contribution
            }
            float s = 0.0f;
#pragma unroll
            for (int d = 0; d < DD; ++d) s = fmaf(zc[u][d], zc[u][d], s);
            s2[u] = s;
        }
        __syncthreads();  // i-tile records ready

        // ---- hot loop: 64 i-rows, barrier-free, row rotated 1 ahead ----
        float acc[JPT] = {0.0f, 0.0f};
        float4 cr0 = *(const float4*)&sIR[0];
        float4 cr1 = *(const float4*)&sIR[4];
        float2 cib = *(const float2*)&sIR[8];
#pragma unroll 4
        for (int a = 0; a < TI; ++a) {
            float4 nr0, nr1; float2 nib;
            if (a + 1 < TI) {              // prefetch next row (broadcast ds_read)
                nr0 = *(const float4*)&sIR[(a + 1) * 12];
                nr1 = *(const float4*)&sIR[(a + 1) * 12 + 4];
                nib = *(const float2*)&sIR[(a + 1) * 12 + 8];
            }
#pragma unroll
            for (int u = 0; u < JPT; ++u) {
                float dd;
                dd = fmaf(cr0.x, zc[u][0], cib.x);     // seed with |ziL|^2
                dd = fmaf(cr0.y, zc[u][1], dd);
                dd = fmaf(cr0.z, zc[u][2], dd);
                dd = fmaf(cr0.w, zc[u][3], dd);
                dd = fmaf(cr1.x, zc[u][4], dd);
                dd = fmaf(cr1.y, zc[u][5], dd);
                dd = fmaf(cr1.z, zc[u][6], dd);
                dd = fmaf(cr1.w, zc[u][7], dd);
                float ss = fmaxf(dd + s2[u], 1e-20f);  // distL^2 (log2-scaled)
                float dist = __builtin_amdgcn_sqrtf(ss);
                float e = __builtin_amdgcn_exp2f(-dist);   // neg = free src modifier
                acc[u] = fmaf(cib.y, e, acc[u]);           // * e^beta_row
            }
            cr0 = nr0; cr1 = nr1; cib = nib;
        }
        float bs = 0.0f;
#pragma unroll
        for (int u = 0; u < JPT; ++u) bs = fmaf(gf[u], acc[u], bs);  // * e^gamma_col
        blocksum = -bs;   // dense term enters LL negatively
    } else {
        // ---------------- sparse link term: Poisson log-likelihood ----------------
        const int base = (blockIdx.x - N_DENSE_BLOCKS) * SPARSE_SPAN + t;
        float val = 0.0f;
        const uint4* hzv = (const uint4*)hz;
#pragma unroll
        for (int u = 0; u < LPT; ++u) {
            const int idx = base + u * 256;
            if (idx >= NNZ_N) continue;
            const int i = spi[idx], j = spj[idx];
            const float c = valueC[idx];
            float dist, bg;
            if (MODE == 0) {
                // fp16 packed path: 16B/row gathers, fp16 biases (L2-resident)
                uint4 ui = hzv[i];
                uint4 uj = hzv[NI_TOT + j];
                float fi[DD], fj[DD];
                unpack_row(ui, fi);
                unpack_row(uj, fj);
                float ss = 0.0f;
#pragma unroll
                for (int d = 0; d < DD; ++d) {
                    float df = fi[d] - fj[d] + EPSF;
                    ss = fmaf(df, df, ss);
                }
                ss = fmaxf(ss, 1e-20f);
                dist = __builtin_amdgcn_sqrtf(ss);
                bg = __half2float(hb[i]) + __half2float(hb[NI_TOT + j]);
            } else {
                // f32 fallback (no workspace)
                const float4* zi4 = (const float4*)(zi_all + (size_t)i * DD);
                const float4* zj4 = (const float4*)(zj_all + (size_t)j * DD);
                float4 a0 = zi4[0], a1 = zi4[1];
                float4 b0 = zj4[0], b1 = zj4[1];
                float ss = 0.0f, df;
                df = a0.x-b0.x+EPSF; ss = fmaf(df,df,ss);
                df = a0.y-b0.y+EPSF; ss = fmaf(df,df,ss);
                df = a0.z-b0.z+EPSF; ss = fmaf(df,df,ss);
                df = a0.w-b0.w+EPSF; ss = fmaf(df,df,ss);
                df = a1.x-b1.x+EPSF; ss = fmaf(df,df,ss);
                df = a1.y-b1.y+EPSF; ss = fmaf(df,df,ss);
                df = a1.z-b1.z+EPSF; ss = fmaf(df,df,ss);
                df = a1.w-b1.w+EPSF; ss = fmaf(df,df,ss);
                ss = fmaxf(ss, 1e-20f);
                dist = __builtin_amdgcn_sqrtf(ss);
                bg = beta[i] + gamma[j];
            }
            // gammaln(c+1) via A&S 6.1.36 poly (|e|<=3e-7), ln = log2/log2e
            float g = 1.0f + c*(GA1 + c*(GA2 + c*(GA3 + c*(GA4 + c*(GA5
                          + c*(GA6 + c*(GA7 + c*GA8)))))));
            val += c * (bg - dist) - __builtin_amdgcn_logf(g) * INV_LOG2E;
        }
        blocksum = val;  // positive sign
    }

    // Block reduction: wave shuffle then cross-wave via LDS
    float acc = blocksum;
#pragma unroll
    for (int off = 32; off; off >>= 1) acc += __shfl_down(acc, off, 64);
    const int lane = t & 63, w = t >> 6;
    if (lane == 0) sRed[w] = acc;
    __syncthreads();

    if (MODE == 0) {
        // Last-block ticket reduction (R4-validated): fold final_reduce dispatch.
        if (t == 0) {
            float s = sRed[0] + sRed[1] + sRed[2] + sRed[3];
            partials[blockIdx.x] = s;
            __threadfence();                          // publish partial
            unsigned tk = atomicAdd(ticket, 1u);      // device-scope RMW
            lastFlag = (tk == (unsigned)(N_TOTAL_BLOCKS - 1));
        }
        __syncthreads();
        if (lastFlag) {
            __threadfence();                          // acquire side
            float s = 0.0f;
            for (int i2 = t; i2 < N_TOTAL_BLOCKS; i2 += 256) s += partials[i2];
#pragma unroll
            for (int off = 32; off; off >>= 1) s += __shfl_down(s, off, 64);
            if (lane == 0) sRed[w] = s;
            __syncthreads();
            if (t == 0) out[0] = sRed[0] + sRed[1] + sRed[2] + sRed[3];
        }
    } else {
        if (t == 0) {
            float s = sRed[0] + sRed[1] + sRed[2] + sRed[3];
            atomicAdd(out, s);
        }
    }
}

extern "C" void kernel_launch(void* const* d_in, const int* in_sizes, int n_in,
                              void* d_out, int out_size, void* d_ws, size_t ws_size,
                              hipStream_t stream) {
    const float* beta   = (const float*)d_in[0];
    const float* gamma  = (const float*)d_in[1];
    const float* zi     = (const float*)d_in[2];
    const float* zj     = (const float*)d_in[3];
    const float* valueC = (const float*)d_in[4];
    const int* si   = (const int*)d_in[5];
    const int* sjx  = (const int*)d_in[6];
    const int* spi  = (const int*)d_in[7];
    const int* spj  = (const int*)d_in[8];
    float* out = (float*)d_out;

    if (d_ws && ws_size >= WS_NEED) {
        __half* hz = (__half*)d_ws;
        __half* hb = (__half*)((char*)d_ws + HZ_BYTES);
        float* irec = (float*)((char*)d_ws + IREC_OFF);
        float* p = (float*)((char*)d_ws + PART_OFF);
        unsigned* ticket = (unsigned*)((char*)d_ws + TICKET_OFF);
        const int packb = (2 * NROWS + IREC_N + 255) / 256;   // 1587
        pack_kernel<<<packb, 256, 0, stream>>>(beta, gamma, zi, zj, si,
                                               hz, hb, irec, ticket);
        fused_kernel<0><<<N_TOTAL_BLOCKS, 256, 0, stream>>>(
            beta, gamma, zi, zj, valueC, si, sjx, spi, spj,
            hz, hb, irec, p, ticket, out);
    } else {
        // Fallback: f32 sparse + atomic accumulation directly into d_out
        hipMemsetAsync(out, 0, sizeof(float), stream);
        fused_kernel<1><<<N_TOTAL_BLOCKS, 256, 0, stream>>>(
            beta, gamma, zi, zj, valueC, si, sjx, spi, spj,
            nullptr, nullptr, nullptr, nullptr, nullptr, out);
    }
}

// Round 6
// 106.745 us; speedup vs baseline: 1.4458x; 1.4458x over previous
//
#include <hip/hip_runtime.h>
#include <hip/hip_fp16.h>
#include <math.h>

// Problem constants (fixed by reference)
#define NI_TOT 100000
#define NJ_TOT 100000
#define DD 8
#define SI_N 6000
#define SJ_N 6000
#define NNZ_N 500000
#define EPSF 1e-6f
#define LOG2E 1.44269504088896f
#define INV_LOG2E 0.693147180559945f
#define L2SQ (LOG2E * LOG2E)

// Dense geometry: block = 64 i-rows (LDS) x 512 j-cols (2/thread in regs).
// R2 lesson: grid must stay >= ~2048 blocks (latency-bound, needs residency).
// R4 lesson: i-rows via LDS broadcast, NOT scalar s_load chains (2x slower).
// R4/R5 lesson: ticket+__threadfence epilogue costs ~40-50us (agent-scope
// release -> per-block L2 writeback serializing at each XCD). Use the
// 3-dispatch partials+final_reduce structure (R3, best measured).
// R5 diagnosis: dense hot loop is CU-level LDS-PIPE-bound (32 waves x 30cyc
// ds_read vs ~608cyc VALU per round) -> this round halves LDS bytes via
// fp16 rows + v_dot2_f32_f16 (fp16 z already validated by sparse path).
#define TI 64
#define JPT 2
#define JTILE (256 * JPT)                     // 512
#define ND_I ((SI_N + TI - 1) / TI)           // 94
#define NJT ((SJ_N + JTILE - 1) / JTILE)      // 12
#define N_DENSE_BLOCKS (ND_I * NJT)           // 1128
// Sparse: 2 links per thread
#define LPT 2
#define SPARSE_SPAN (256 * LPT)               // 512
#define N_SPARSE_BLOCKS ((NNZ_N + SPARSE_SPAN - 1) / SPARSE_SPAN) // 977
#define N_TOTAL_BLOCKS (N_DENSE_BLOCKS + N_SPARSE_BLOCKS)         // 2105

// Workspace layout: [fp16 z rows: 200K x 16B][fp16 biases: 200K x 2B][partials]
// fp16 cache keeps sparse gather footprint 3.6MB (L2-resident per XCD);
// R1 measured: dropping it cost 44MB HBM FETCH.
#define NROWS (NI_TOT + NJ_TOT)
#define HZ_BYTES ((size_t)NROWS * DD * 2)     // 3.2 MB
#define HB_BYTES ((size_t)NROWS * 2)          // 400 KB
#define PARTIALS_OFF (HZ_BYTES + HB_BYTES)    // 3.6 MB (16B aligned)

// A&S 6.1.36: Gamma(1+x) = 1 + a1 x + ... + a8 x^8, 0<=x<=1, |eps|<=3e-7
#define GA1 (-0.577191652f)
#define GA2 ( 0.988205891f)
#define GA3 (-0.897056937f)
#define GA4 ( 0.918206857f)
#define GA5 (-0.756704078f)
#define GA6 ( 0.482199394f)
#define GA7 (-0.193527818f)
#define GA8 ( 0.035868343f)

typedef _Float16 h2 __attribute__((ext_vector_type(2)));

#if defined(__has_builtin)
#if __has_builtin(__builtin_amdgcn_fdot2)
#define HAVE_FDOT2 1
#endif
#endif

__device__ __forceinline__ h2 u2h(unsigned u) {
    union { unsigned v; h2 h; } c; c.v = u; return c.h;
}
__device__ __forceinline__ unsigned pack2h(float x, float y) {
    union { unsigned v; h2 h; } c;
    c.h[0] = (_Float16)x; c.h[1] = (_Float16)y;
    return c.v;
}
__device__ __forceinline__ float fdot2f(h2 a, h2 b, float c) {
#ifdef HAVE_FDOT2
    return __builtin_amdgcn_fdot2(a, b, c, false);
#else
    return fmaf((float)a[0], (float)b[0], fmaf((float)a[1], (float)b[1], c));
#endif
}

// ---- prep: pack z rows (16B/row) and biases to fp16 in workspace ----
__global__ __launch_bounds__(256) void pack_kernel(
    const float* __restrict__ beta, const float* __restrict__ gamma,
    const float* __restrict__ zi_all, const float* __restrict__ zj_all,
    __half* __restrict__ hz, __half* __restrict__ hb)
{
    const int r = blockIdx.x * 256 + threadIdx.x;
    if (r < NROWS) {
        const float* src = (r < NI_TOT) ? zi_all + (size_t)r * DD
                                        : zj_all + (size_t)(r - NI_TOT) * DD;
        float4 a = ((const float4*)src)[0];
        float4 b = ((const float4*)src)[1];
        __half2 h0 = __floats2half2_rn(a.x, a.y);
        __half2 h1 = __floats2half2_rn(a.z, a.w);
        __half2 h2v = __floats2half2_rn(b.x, b.y);
        __half2 h3 = __floats2half2_rn(b.z, b.w);
        uint4 u;
        u.x = *(unsigned*)&h0; u.y = *(unsigned*)&h1;
        u.z = *(unsigned*)&h2v; u.w = *(unsigned*)&h3;
        ((uint4*)hz)[r] = u;
    } else if (r < 2 * NROWS) {
        const int q = r - NROWS;
        float v = (q < NI_TOT) ? beta[q] : gamma[q - NI_TOT];
        hb[q] = __float2half(v);
    }
}

__device__ __forceinline__ void unpack_row(uint4 u, float f[DD]) {
    float2 p;
    p = __half22float2(*(__half2*)&u.x); f[0] = p.x; f[1] = p.y;
    p = __half22float2(*(__half2*)&u.y); f[2] = p.x; f[3] = p.y;
    p = __half22float2(*(__half2*)&u.z); f[4] = p.x; f[5] = p.y;
    p = __half22float2(*(__half2*)&u.w); f[6] = p.x; f[7] = p.y;
}

template<int MODE>   // 0 = workspace path, 1 = f32 fallback (atomic out)
__global__ __launch_bounds__(256) void fused_kernel(
    const float* __restrict__ beta, const float* __restrict__ gamma,
    const float* __restrict__ zi_all, const float* __restrict__ zj_all,
    const float* __restrict__ valueC,
    const int* __restrict__ si, const int* __restrict__ sj,       // dense samples
    const int* __restrict__ spi, const int* __restrict__ spj,     // sparse links
    const __half* __restrict__ hz, const __half* __restrict__ hb, // fp16 packed
    float* __restrict__ partials, float* __restrict__ out)
{
    __shared__ float sRed[4];
    // Dense i-tile: per row 32B = {4x half2 m_d, f32 seedL, f32 e^beta, pad2}
    // m_d = -2*L^2*(zi_d+EPS) in fp16; seedL = L^2*|zi+EPS|^2 (f32, pre-round).
    __shared__ __align__(16) unsigned sRow[TI * 8];

    const int t = threadIdx.x;
    float blocksum = 0.0f;  // signed contribution of this block to LL

    if (blockIdx.x < N_DENSE_BLOCKS) {
        // -------- dense non-link: -sum(exp(beta_i + gamma_j - |zi-zj|)) --------
        // e^{b+g-d} = (e^b)_row * (e^g)_col * exp2(-L*d).
        // (L*d)^2 = L^2|a|^2 + L^2|b|^2 + sum(m_d * b_d), a = zi+EPS, b = zj,
        // m = -2 L^2 a  -> 4 chained fdot2 seeded with L^2|a|^2.
        const int it = blockIdx.x % ND_I;
        const int js = blockIdx.x / ND_I;
        const int i0 = it * TI;

        // Stage i-tile rows: one wave, 64 rows, 16B gathers.
        if (t < TI) {
            const int gi = i0 + t;
            uint4 mh = make_uint4(0u, 0u, 0u, 0u);
            float seedL = 0.f, eb = 0.f;     // pad row -> zero contribution
            if (gi < SI_N) {
                const int row = si[gi];
                float a[DD];
                if (MODE == 0) {
                    uint4 raw = ((const uint4*)hz)[row];
                    float f[DD]; unpack_row(raw, f);
#pragma unroll
                    for (int d = 0; d < DD; ++d) a[d] = f[d] + EPSF;
                } else {
                    const float4* zp = (const float4*)(zi_all + (size_t)row * DD);
                    float4 p0 = zp[0], p1 = zp[1];
                    a[0]=p0.x+EPSF; a[1]=p0.y+EPSF; a[2]=p0.z+EPSF; a[3]=p0.w+EPSF;
                    a[4]=p1.x+EPSF; a[5]=p1.y+EPSF; a[6]=p1.z+EPSF; a[7]=p1.w+EPSF;
                }
                float s = 0.f;
#pragma unroll
                for (int d = 0; d < DD; ++d) s = fmaf(a[d], a[d], s);
                seedL = s * L2SQ;
                eb = __builtin_amdgcn_exp2f(beta[row] * LOG2E);
                const float k = -2.0f * L2SQ;
                mh.x = pack2h(a[0]*k, a[1]*k);
                mh.y = pack2h(a[2]*k, a[3]*k);
                mh.z = pack2h(a[4]*k, a[5]*k);
                mh.w = pack2h(a[6]*k, a[7]*k);
            }
            *(uint4*)&sRow[t * 8] = mh;
            sRow[t * 8 + 4] = __float_as_uint(seedL);
            sRow[t * 8 + 5] = __float_as_uint(eb);
        }

        // Gather this thread's 2 j-columns (fp16) into registers.
        const int jb = js * JTILE + t * JPT;
        uint4 ch[JPT]; float s2[JPT], gf[JPT];
#pragma unroll
        for (int u = 0; u < JPT; ++u) {
            int gj = jb + u;
            if (gj < SJ_N) {
                int row = sj[gj];
                if (MODE == 0) {
                    ch[u] = ((const uint4*)hz)[NI_TOT + row];
                } else {
                    const float4* q = (const float4*)(zj_all + (size_t)row * DD);
                    float4 q0 = q[0], q1 = q[1];
                    ch[u].x = pack2h(q0.x, q0.y); ch[u].y = pack2h(q0.z, q0.w);
                    ch[u].z = pack2h(q1.x, q1.y); ch[u].w = pack2h(q1.z, q1.w);
                }
                float s = fdot2f(u2h(ch[u].x), u2h(ch[u].x),
                          fdot2f(u2h(ch[u].y), u2h(ch[u].y),
                          fdot2f(u2h(ch[u].z), u2h(ch[u].z),
                          fdot2f(u2h(ch[u].w), u2h(ch[u].w), 0.0f))));
                s2[u] = s * L2SQ;                          // L^2 |b|^2
                gf[u] = __builtin_amdgcn_exp2f(gamma[row] * LOG2E);
            } else {
                ch[u] = make_uint4(0u, 0u, 0u, 0u);
                s2[u] = 0.0f;
                gf[u] = 0.0f;  // pad col -> zero contribution
            }
        }
        __syncthreads();  // i-tile ready

        // ---- hot loop: 64 i-rows, barrier-free, row rotated 1 ahead ----
        // LDS per iter: ds_read_b128 + ds_read_b64 (24B payload; was 40B/3 reads)
        float acc[JPT] = {0.0f, 0.0f};
        uint4  cr  = *(const uint4*)&sRow[0];
        float2 cib = *(const float2*)&sRow[4];
#pragma unroll 4
        for (int a = 0; a < TI; ++a) {
            uint4 nr; float2 nib;
            if (a + 1 < TI) {              // prefetch next row (broadcast ds_read)
                nr  = *(const uint4*)&sRow[(a + 1) * 8];
                nib = *(const float2*)&sRow[(a + 1) * 8 + 4];
            }
#pragma unroll
            for (int u = 0; u < JPT; ++u) {
                float dd;
                dd = fdot2f(u2h(cr.x), u2h(ch[u].x), cib.x);  // seed L^2|a|^2
                dd = fdot2f(u2h(cr.y), u2h(ch[u].y), dd);
                dd = fdot2f(u2h(cr.z), u2h(ch[u].z), dd);
                dd = fdot2f(u2h(cr.w), u2h(ch[u].w), dd);
                float ss = fmaxf(dd + s2[u], 1e-20f);  // (L*dist)^2
                float dist = __builtin_amdgcn_sqrtf(ss);
                float e = __builtin_amdgcn_exp2f(-dist);   // neg = free src modifier
                acc[u] = fmaf(cib.y, e, acc[u]);           // * e^beta_row
            }
            cr = nr; cib = nib;
        }
        float bs = 0.0f;
#pragma unroll
        for (int u = 0; u < JPT; ++u) bs = fmaf(gf[u], acc[u], bs);  // * e^gamma_col
        blocksum = -bs;   // dense term enters LL negatively
    } else {
        // ---------------- sparse link term: Poisson log-likelihood ----------------
        const int base = (blockIdx.x - N_DENSE_BLOCKS) * SPARSE_SPAN + t;
        float val = 0.0f;
        const uint4* hzv = (const uint4*)hz;
#pragma unroll
        for (int u = 0; u < LPT; ++u) {
            const int idx = base + u * 256;
            if (idx >= NNZ_N) continue;
            const int i = spi[idx], j = spj[idx];
            const float c = valueC[idx];
            float dist, bg;
            if (MODE == 0) {
                // fp16 packed path: 16B/row gathers, fp16 biases (L2-resident)
                uint4 ui = hzv[i];
                uint4 uj = hzv[NI_TOT + j];
                float fi[DD], fj[DD];
                unpack_row(ui, fi);
                unpack_row(uj, fj);
                float ss = 0.0f;
#pragma unroll
                for (int d = 0; d < DD; ++d) {
                    float df = fi[d] - fj[d] + EPSF;
                    ss = fmaf(df, df, ss);
                }
                ss = fmaxf(ss, 1e-20f);
                dist = __builtin_amdgcn_sqrtf(ss);
                bg = __half2float(hb[i]) + __half2float(hb[NI_TOT + j]);
            } else {
                // f32 fallback (no workspace)
                const float4* zi4 = (const float4*)(zi_all + (size_t)i * DD);
                const float4* zj4 = (const float4*)(zj_all + (size_t)j * DD);
                float4 a0 = zi4[0], a1 = zi4[1];
                float4 b0 = zj4[0], b1 = zj4[1];
                float ss = 0.0f, df;
                df = a0.x-b0.x+EPSF; ss = fmaf(df,df,ss);
                df = a0.y-b0.y+EPSF; ss = fmaf(df,df,ss);
                df = a0.z-b0.z+EPSF; ss = fmaf(df,df,ss);
                df = a0.w-b0.w+EPSF; ss = fmaf(df,df,ss);
                df = a1.x-b1.x+EPSF; ss = fmaf(df,df,ss);
                df = a1.y-b1.y+EPSF; ss = fmaf(df,df,ss);
                df = a1.z-b1.z+EPSF; ss = fmaf(df,df,ss);
                df = a1.w-b1.w+EPSF; ss = fmaf(df,df,ss);
                ss = fmaxf(ss, 1e-20f);
                dist = __builtin_amdgcn_sqrtf(ss);
                bg = beta[i] + gamma[j];
            }
            // gammaln(c+1) via A&S 6.1.36 poly (|e|<=3e-7), ln = log2/log2e
            float g = 1.0f + c*(GA1 + c*(GA2 + c*(GA3 + c*(GA4 + c*(GA5
                          + c*(GA6 + c*(GA7 + c*GA8)))))));
            val += c * (bg - dist) - __builtin_amdgcn_logf(g) * INV_LOG2E;
        }
        blocksum = val;  // positive sign
    }

    // Block reduction: wave shuffle then cross-wave via LDS
    float acc = blocksum;
#pragma unroll
    for (int off = 32; off; off >>= 1) acc += __shfl_down(acc, off, 64);
    const int lane = t & 63, w = t >> 6;
    if (lane == 0) sRed[w] = acc;
    __syncthreads();
    if (t == 0) {
        float s = sRed[0] + sRed[1] + sRed[2] + sRed[3];
        if (MODE) atomicAdd(out, s);
        else partials[blockIdx.x] = s;
    }
}

__global__ __launch_bounds__(256) void final_reduce_kernel(
    const float* __restrict__ p, int n, float* __restrict__ out)
{
    __shared__ float sRed[4];
    float s0 = 0.0f, s1 = 0.0f, s2 = 0.0f, s3 = 0.0f;
    int i = threadIdx.x;
    for (; i + 768 < n; i += 1024) {      // 4 independent chains to pipeline loads
        s0 += p[i]; s1 += p[i + 256]; s2 += p[i + 512]; s3 += p[i + 768];
    }
    for (; i < n; i += 256) s0 += p[i];
    float s = (s0 + s1) + (s2 + s3);
#pragma unroll
    for (int off = 32; off; off >>= 1) s += __shfl_down(s, off, 64);
    const int lane = threadIdx.x & 63, w = threadIdx.x >> 6;
    if (lane == 0) sRed[w] = s;
    __syncthreads();
    if (threadIdx.x == 0) out[0] = sRed[0] + sRed[1] + sRed[2] + sRed[3];
}

extern "C" void kernel_launch(void* const* d_in, const int* in_sizes, int n_in,
                              void* d_out, int out_size, void* d_ws, size_t ws_size,
                              hipStream_t stream) {
    const float* beta   = (const float*)d_in[0];
    const float* gamma  = (const float*)d_in[1];
    const float* zi     = (const float*)d_in[2];
    const float* zj     = (const float*)d_in[3];
    const float* valueC = (const float*)d_in[4];
    const int* si   = (const int*)d_in[5];
    const int* sjx  = (const int*)d_in[6];
    const int* spi  = (const int*)d_in[7];
    const int* spj  = (const int*)d_in[8];
    float* out = (float*)d_out;

    const int ntot = N_TOTAL_BLOCKS;
    const size_t need = PARTIALS_OFF + (size_t)ntot * sizeof(float);

    if (d_ws && ws_size >= need) {
        __half* hz = (__half*)d_ws;
        __half* hb = (__half*)((char*)d_ws + HZ_BYTES);
        float* p = (float*)((char*)d_ws + PARTIALS_OFF);
        const int packb = (2 * NROWS + 255) / 256;      // 1563
        pack_kernel<<<packb, 256, 0, stream>>>(beta, gamma, zi, zj, hz, hb);
        fused_kernel<0><<<ntot, 256, 0, stream>>>(
            beta, gamma, zi, zj, valueC, si, sjx, spi, spj, hz, hb, p, out);
        final_reduce_kernel<<<1, 256, 0, stream>>>(p, ntot, out);
    } else {
        // Fallback: f32 sparse + atomic accumulation directly into d_out
        hipMemsetAsync(out, 0, sizeof(float), stream);
        fused_kernel<1><<<ntot, 256, 0, stream>>>(
            beta, gamma, zi, zj, valueC, si, sjx, spi, spj,
            (const __half*)zi, (const __half*)zi, nullptr, out);
    }
}